// Round 24
// baseline (297.141 us; speedup 1.0000x reference)
//
#include <hip/hip_runtime.h>
#include <hip/hip_bf16.h>
#include <math.h>

#define HID 128
#define PR 20      // rows per pool block
#define CRPB 32    // conv rows per block
#define CAND_CAP 8192
#define MAXCELLS 4096

__device__ inline int wave_iscan(int v, int lane) {   // inclusive scan within 64-lane wave
#pragma unroll
  for (int off = 1; off < 64; off <<= 1) {
    int o = __shfl_up(v, off, 64);
    if (lane >= off) v += o;
  }
  return v;
}

// ---------- fused mean-gather + GraphConv + score-scalar epilogue ----------
// sx staging removed: x[row][cq] is read as a broadcast global load in the GEMM
// loop (all 32 lanes of a row-group hit the same float4 -> one L1 transaction).
// Bit-exact vs r23 (same operand values, same FMA order). LDS 33.8KB -> ~17KB
// doubles blocks/CU (4 -> 9) to hide the gather latency.
template <int K>
__global__ __launch_bounds__(256) void k_conv_fused(
    const float* __restrict__ x, const int* __restrict__ src, int n, float invk,
    const float* __restrict__ Wrel, const float* __restrict__ Wroot,
    const float* __restrict__ brel,
    const float* __restrict__ wprel, const float* __restrict__ wproot,
    float* __restrict__ out, float* __restrict__ uo, float* __restrict__ vo) {
  __shared__ float4 sagg4[CRPB][HID / 4];
  __shared__ int ssrc[CRPB * K];
  int t = threadIdx.x;
  int i0 = blockIdx.x * CRPB;
  const int nK = n * K;
  for (int s = t; s < CRPB * K; s += 256) {
    int gi = i0 * K + s;
    int v = (gi < nK) ? src[gi] : 0;
    ssrc[s] = ((unsigned)v < (unsigned)n) ? v : 0;
  }
  __syncthreads();
  const float4* x4 = (const float4*)x;
  {
    int fq = t & 31, h = t >> 5;
    for (int r = h; r < CRPB; r += 8) {
      int row = i0 + r;
      float4 s = make_float4(0.f, 0.f, 0.f, 0.f);
      if (row < n) {
#pragma unroll
        for (int j = 0; j < K; ++j) {
          float4 xx = x4[(size_t)ssrc[r * K + j] * 32 + fq];
          s.x += xx.x; s.y += xx.y; s.z += xx.z; s.w += xx.w;
        }
      }
      s.x *= invk; s.y *= invk; s.z *= invk; s.w *= invk;
      sagg4[r][fq] = s;
    }
  }
  __syncthreads();
  int q = t & 31, rg = t >> 5;
  const float4* Wrel4  = (const float4*)Wrel;
  const float4* Wroot4 = (const float4*)Wroot;
  float4 bq = ((const float4*)brel)[q];
  float4 acc[4];
#pragma unroll
  for (int rr = 0; rr < 4; ++rr) acc[rr] = bq;
  int rbase = rg * 4;
#pragma unroll 2
  for (int cq = 0; cq < HID / 4; ++cq) {
    float4 w1[4], w2[4];
#pragma unroll
    for (int uu = 0; uu < 4; ++uu) {
      w1[uu] = Wrel4[(cq * 4 + uu) * 32 + q];
      w2[uu] = Wroot4[(cq * 4 + uu) * 32 + q];
    }
#pragma unroll
    for (int rr = 0; rr < 4; ++rr) {
      int row = i0 + rbase + rr;
      float4 a  = sagg4[rbase + rr][cq];
      float4 xx = (row < n) ? x4[(size_t)row * 32 + cq]
                            : make_float4(0.f, 0.f, 0.f, 0.f);
      acc[rr].x += a.x*w1[0].x + a.y*w1[1].x + a.z*w1[2].x + a.w*w1[3].x
                 + xx.x*w2[0].x + xx.y*w2[1].x + xx.z*w2[2].x + xx.w*w2[3].x;
      acc[rr].y += a.x*w1[0].y + a.y*w1[1].y + a.z*w1[2].y + a.w*w1[3].y
                 + xx.x*w2[0].y + xx.y*w2[1].y + xx.z*w2[2].y + xx.w*w2[3].y;
      acc[rr].z += a.x*w1[0].z + a.y*w1[1].z + a.z*w1[2].z + a.w*w1[3].z
                 + xx.x*w2[0].z + xx.y*w2[1].z + xx.z*w2[2].z + xx.w*w2[3].z;
      acc[rr].w += a.x*w1[0].w + a.y*w1[1].w + a.z*w1[2].w + a.w*w1[3].w
                 + xx.x*w2[0].w + xx.y*w2[1].w + xx.z*w2[2].w + xx.w*w2[3].w;
    }
  }
  float4 wplq = ((const float4*)wprel)[q];
  float4 wprq = ((const float4*)wproot)[q];
#pragma unroll
  for (int rr = 0; rr < 4; ++rr) {
    int row = i0 + rbase + rr;
    float4 v = acc[rr];
    v.x = v.x > 0.f ? v.x : 0.f;
    v.y = v.y > 0.f ? v.y : 0.f;
    v.z = v.z > 0.f ? v.z : 0.f;
    v.w = v.w > 0.f ? v.w : 0.f;
    float pu = 0.f, pv = 0.f;
    if (row < n) {
      ((float4*)out)[(size_t)row * 32 + q] = v;
      pu = v.x * wplq.x + v.y * wplq.y + v.z * wplq.z + v.w * wplq.w;
      pv = v.x * wprq.x + v.y * wprq.y + v.z * wprq.z + v.w * wprq.w;
    }
#pragma unroll
    for (int o = 16; o; o >>= 1) {
      pu += __shfl_down(pu, o, 32);
      pv += __shfl_down(pv, o, 32);
    }
    if (q == 0 && row < n) { uo[row] = pu; vo[row] = pv; }
  }
}

// ---------- scalar score + fused per-block 1024-bin histogram ----------
template <int K>
__global__ __launch_bounds__(256) void k_score_lite(
    const float* __restrict__ u, const float* __restrict__ v,
    const int* __restrict__ src, const float* __restrict__ bprel,
    int n, float* __restrict__ score, unsigned* __restrict__ key,
    unsigned* __restrict__ ghist) {
  __shared__ unsigned lh[1024];
  int t = threadIdx.x;
#pragma unroll
  for (int uu = 0; uu < 4; ++uu) lh[t + uu * 256] = 0u;
  __syncthreads();
  int i = blockIdx.x * 256 + t;
  if (i < n) {
    float s = v[i] + bprel[0];
#pragma unroll
    for (int j = 0; j < K; ++j) s += u[src[i * K + j]];
    float sc = tanhf(s);
    score[i] = sc;
    unsigned bb = __float_as_uint(sc);
    unsigned k2 = (bb & 0x80000000u) ? ~bb : (bb | 0x80000000u);
    key[i] = k2;
    atomicAdd(&lh[k2 >> 22], 1u);
  }
  __syncthreads();
#pragma unroll
  for (int uu = 0; uu < 4; ++uu) {
    unsigned vv = lh[t + uu * 256];
    if (vv) atomicAdd(&ghist[t + uu * 256], vv);
  }
}

// ---------- collect: inline boundary-bin pick + u64 candidate append ----------
__global__ __launch_bounds__(256) void k_collect(
    const unsigned* __restrict__ key, int n, int kk,
    const unsigned* __restrict__ ghist,
    unsigned* __restrict__ BA, unsigned long long* __restrict__ candbuf,
    int* __restrict__ candCnt) {
  __shared__ int wt[4];
  __shared__ unsigned shB, shAbove;
  int t = threadIdx.x;             // 256
  int lane = t & 63, wid = t >> 6;
  unsigned h[4]; int s = 0;
#pragma unroll
  for (int uu = 0; uu < 4; ++uu) { h[uu] = ghist[t * 4 + uu]; s += (int)h[uu]; }
  int is = wave_iscan(s, lane);
  if (lane == 63) wt[wid] = is;
  __syncthreads();
  int b = 0, tot = 0;
#pragma unroll
  for (int w2 = 0; w2 < 4; ++w2) { int ss = wt[w2]; if (w2 < wid) b += ss; tot += ss; }
  int c = b + is - s;
#pragma unroll
  for (int uu = 0; uu < 4; ++uu) {
    c += (int)h[uu];
    unsigned above_strict = (unsigned)(tot - c);
    unsigned above_incl = above_strict + h[uu];
    if (above_incl >= (unsigned)kk && above_strict < (unsigned)kk) {
      shB = (unsigned)(t * 4 + uu);
      shAbove = above_strict;
    }
  }
  __syncthreads();
  unsigned B = shB;
  if (blockIdx.x == 0 && t == 0) { BA[0] = B; BA[1] = shAbove; }
  int i = blockIdx.x * 256 + t;
  unsigned long long lmask = (1ull << lane) - 1ull;
  unsigned kv = (i < n) ? key[i] : 0u;
  bool m = (i < n) && ((kv >> 22) == B);
  unsigned long long mm = __ballot(m);
  if (mm) {
    int leader = (int)(__ffsll((long long)mm) - 1);
    int base = 0;
    if (lane == leader) base = atomicAdd(candCnt, (int)__popcll(mm));
    base = __shfl(base, leader, 64);
    if (m) {
      int p = base + (int)__popcll(mm & lmask);
      if (p < CAND_CAP) candbuf[p] = ((unsigned long long)kv << 32) | (unsigned)(~i);
    }
  }
}

// ---------- refine 54 remaining bits of unique key64 -> exact T64 ----------
__global__ __launch_bounds__(1024) void k_refine(
    const unsigned long long* __restrict__ candbuf, const int* __restrict__ candCnt,
    const unsigned* __restrict__ BA, int kk, unsigned long long* __restrict__ T64) {
  extern __shared__ unsigned long long cands[];   // CAND_CAP u64 = 64 KB
  __shared__ unsigned hist256[256];
  __shared__ unsigned long long sh_prefix;
  __shared__ unsigned sh_remain;
  __shared__ int wtB[4];
  int t = threadIdx.x;
  int lane = t & 63, wid = t >> 6;
  unsigned B = BA[0], above = BA[1];
  int cnt = *candCnt; if (cnt > CAND_CAP) cnt = CAND_CAP;
  for (int i = t; i < cnt; i += 1024) cands[i] = candbuf[i];
  if (t == 0) {
    sh_prefix = ((unsigned long long)B) << 54;
    sh_remain = (unsigned)(kk - (int)above);
  }
  __syncthreads();
  const int shifts[7] = {46, 38, 30, 22, 14, 6, 0};
  for (int p = 0; p < 7; ++p) {
    int shift = shifts[p];
    int bits = (p == 6) ? 6 : 8;
    unsigned mask = (1u << bits) - 1u;
    unsigned long long himask = (p == 0) ? (~0ull << 54)
                                         : (~0ull << (shifts[p - 1]));
    unsigned long long prefix = sh_prefix;
    unsigned rem = sh_remain;
    if (t < 256) hist256[t] = 0u;
    __syncthreads();
    for (int i = t; i < cnt; i += 1024) {
      unsigned long long cc = cands[i];
      if ((cc & himask) == prefix)
        atomicAdd(&hist256[(unsigned)((cc >> shift) & mask)], 1u);
    }
    __syncthreads();
    int hv = (t < 256) ? (int)hist256[t] : 0;
    int iv = wave_iscan(hv, lane);
    if (t < 256 && lane == 63) wtB[wid] = iv;
    __syncthreads();
    if (t < 256) {
      int b = 0, tot = 0;
#pragma unroll
      for (int w2 = 0; w2 < 4; ++w2) { int s = wtB[w2]; if (w2 < wid) b += s; tot += s; }
      unsigned val = (unsigned)(iv + b);
      unsigned sstrict = (unsigned)tot - val;
      if ((unsigned)t <= mask && sstrict < rem && sstrict + (unsigned)hv >= rem) {
        sh_prefix = prefix | ((unsigned long long)t << shift);
        sh_remain = rem - sstrict;
      }
    }
    __syncthreads();
  }
  if (t == 0) T64[0] = sh_prefix;     // unique k-th largest key64
}

// ---------- compaction: keep key64 >= T64 (exactly kk) + cell counting ----------
__global__ void k_sel(const unsigned* __restrict__ key, int n,
                      const unsigned long long* __restrict__ T64,
                      int* __restrict__ perm, int* __restrict__ cntSel,
                      const float* __restrict__ pos_prev, int* __restrict__ counts,
                      int Gg, float inv_w, int docount) {
  int i = blockIdx.x * blockDim.x + threadIdx.x;
  int lane = threadIdx.x & 63;
  unsigned long long lmask = (1ull << lane) - 1ull;
  unsigned long long T = T64[0];
  bool g = false;
  if (i < n) {
    unsigned long long k64 = ((unsigned long long)key[i] << 32) | (unsigned)(~i);
    g = (k64 >= T);
  }
  unsigned long long mg = __ballot(g);
  if (mg) {
    int leader = (int)(__ffsll((long long)mg) - 1);
    int base = 0;
    if (lane == leader) base = atomicAdd(cntSel, (int)__popcll(mg));
    base = __shfl(base, leader, 64);
    if (g) perm[base + (int)__popcll(mg & lmask)] = i;
  }
  if (g && docount) {
    float px = pos_prev[i * 2], py = pos_prev[i * 2 + 1];
    int cx = min(Gg - 1, max(0, (int)(px * inv_w)));
    int cy = min(Gg - 1, max(0, (int)(py * inv_w)));
    atomicAdd(&counts[cy * Gg + cx], 1);
  }
}

// ---------- spatial scatter: perm -> spatial order map (snode) + spos ----------
__global__ __launch_bounds__(256) void k_scatterS(
    const int* __restrict__ perm, int kk, const float* __restrict__ pos_prev,
    int Gg, int cells, float inv_w,
    const int* __restrict__ counts, int* __restrict__ startsg, int* __restrict__ zcur,
    float2* __restrict__ spos, int* __restrict__ snode) {
  __shared__ int sstarts[MAXCELLS];
  __shared__ int wsum[4];
  int t = threadIdx.x;
  int lane = t & 63, wid = t >> 6;
  int base16 = t * 16;
  int c0[16]; int s = 0;
#pragma unroll
  for (int u = 0; u < 16; ++u) {
    int idx = base16 + u;
    c0[u] = (idx < cells) ? counts[idx] : 0;
    s += c0[u];
  }
  int is = wave_iscan(s, lane);
  if (lane == 63) wsum[wid] = is;
  __syncthreads();
  int b = 0;
#pragma unroll
  for (int w2 = 0; w2 < 4; ++w2) { if (w2 < wid) b += wsum[w2]; }
  int excl = b + is - s;
#pragma unroll
  for (int u = 0; u < 16; ++u) {
    int idx = base16 + u;
    if (idx < cells) { sstarts[idx] = excl; excl += c0[u]; }
  }
  __syncthreads();
  if (blockIdx.x == 0) {
    for (int c = t; c < cells; c += 256) startsg[c] = sstarts[c];
  }
  int j = blockIdx.x * 256 + t;
  if (j < kk) {
    int node = perm[j];
    float px = pos_prev[node * 2], py = pos_prev[node * 2 + 1];
    int cx = min(Gg - 1, max(0, (int)(px * inv_w)));
    int cy = min(Gg - 1, max(0, (int)(py * inv_w)));
    int cell = cy * Gg + cx;
    int pp = sstarts[cell] + atomicAdd(&zcur[cell], 1);
    spos[pp] = make_float2(px, py);
    snode[pp] = node;
  }
}

// ---------- pooled gather in SPATIAL order + per-block column-max ----------
template <int R>
__global__ __launch_bounds__(256) void k_pool_pmax(
    const float* __restrict__ x, const float* __restrict__ score,
    const int* __restrict__ snode,
    float* __restrict__ xout, int store, float* __restrict__ pmax) {
  __shared__ float sm[2][HID];
  int f = threadIdx.x & 127;
  int half = threadIdx.x >> 7;
  int j0 = blockIdx.x * R;
  float mx = -1e30f;
  for (int r = half; r < R; r += 2) {
    int j = j0 + r;
    int node = snode[j];
    float v = score[node];
    float val = x[(size_t)node * HID + f] * v;
    if (store) xout[(size_t)j * HID + f] = val;
    mx = fmaxf(mx, val);
  }
  sm[half][f] = mx;
  __syncthreads();
  if (half == 0) pmax[blockIdx.x * HID + f] = fmaxf(sm[0][f], sm[1][f]);
}

// ---------- exact KNN over spatial array; neighbor index = spatial position ----------
template <int K>
__global__ __launch_bounds__(256) void k_knn_wave(const float2* __restrict__ spos,
                           const int* __restrict__ starts, const int* __restrict__ counts,
                           int m, int G, float w, float inv_w, int* __restrict__ src_out) {
  int lane = threadIdx.x & 63;
  int j = blockIdx.x * (blockDim.x >> 6) + (threadIdx.x >> 6);
  if (j >= m) return;
  float2 qp = spos[j];
  int cx = min(G - 1, max(0, (int)(qp.x * inv_w)));
  int cy = min(G - 1, max(0, (int)(qp.y * inv_w)));

  float bd[K]; int bi[K];
#pragma unroll
  for (int t = 0; t < K; ++t) { bd[t] = 1e30f; bi[t] = 0; }

  auto scan_span = [&](int s, int e) {
    for (int p = s + lane; p < e; p += 64) {
      if (p == j) continue;
      float2 pp = spos[p];
      float dx = qp.x - pp.x, dy = qp.y - pp.y;
      float d = dx * dx + dy * dy;
      if (d < bd[K - 1]) {
        float dd = d; int ii = p;
#pragma unroll
        for (int t = 0; t < K; ++t) {
          bool sw = dd < bd[t];
          float od = bd[t]; int oi = bi[t];
          if (sw) { bd[t] = dd; bi[t] = ii; dd = od; ii = oi; }
        }
      }
    }
  };

  {
    int xl = max(0, cx - 1), xh = min(G - 1, cx + 1);
    int y0 = max(0, cy - 1), y1 = min(G - 1, cy + 1);
    int ss[3], ee[3]; int nr = 0;
    for (int y = y0; y <= y1; ++y) {
      int b = y * G;
      ss[nr] = starts[b + xl];
      ee[nr] = starts[b + xh] + counts[b + xh];
      ++nr;
    }
    for (int t = 0; t < nr; ++t) scan_span(ss[t], ee[t]);
  }

  int r = 1;
  unsigned long long mg[K];
  while (true) {
    unsigned long long tmp[K];
#pragma unroll
    for (int t = 0; t < K; ++t)
      tmp[t] = ((unsigned long long)__float_as_uint(bd[t]) << 32) | (unsigned)bi[t];
#pragma unroll
    for (int t = 0; t < K; ++t) {
      unsigned long long mn = tmp[0];
#pragma unroll
      for (int o = 1; o < 64; o <<= 1) {
        unsigned long long ot = __shfl_xor(mn, o, 64);
        if (ot < mn) mn = ot;
      }
      mg[t] = mn;
      if (tmp[0] == mn) {
#pragma unroll
        for (int s2 = 0; s2 < K - 1; ++s2) tmp[s2] = tmp[s2 + 1];
        tmp[K - 1] = ~0ull;
      }
    }
    float kth = __uint_as_float((unsigned)(mg[K - 1] >> 32));
    float bnd = 1e30f;
    if (cx - r > 0)     bnd = fminf(bnd, qp.x - (float)(cx - r) * w);
    if (cx + r < G - 1) bnd = fminf(bnd, (float)(cx + r + 1) * w - qp.x);
    if (cy - r > 0)     bnd = fminf(bnd, qp.y - (float)(cy - r) * w);
    if (cy + r < G - 1) bnd = fminf(bnd, (float)(cy + r + 1) * w - qp.y);
    if (bnd > 1e29f) break;
    float bb = fmaxf(bnd, 0.f) * 0.999f;
    if (kth < bb * bb) break;
    ++r;
    int xl = max(0, cx - r), xh = min(G - 1, cx + r);
    int yt = cy - r, yb = cy + r;
    if (yt >= 0)     { int b = yt * G; scan_span(starts[b + xl], starts[b + xh] + counts[b + xh]); }
    if (yb <= G - 1) { int b = yb * G; scan_span(starts[b + xl], starts[b + xh] + counts[b + xh]); }
    int ylo = max(0, cy - r + 1), yhi = min(G - 1, cy + r - 1);
    for (int y = ylo; y <= yhi; ++y) {
      int b = y * G;
      if (cx - r >= 0)     { int c = b + cx - r; scan_span(starts[c], starts[c] + counts[c]); }
      if (cx + r <= G - 1) { int c = b + cx + r; scan_span(starts[c], starts[c] + counts[c]); }
    }
  }
  if (lane == 0) {
#pragma unroll
    for (int t = 0; t < K; ++t) src_out[j * K + t] = (int)(unsigned)(mg[t] & 0xffffffffu);
  }
}

// ---------- grid-parallel pmax reduction: 24 blocks -> pmax2[3][8][HID] ----------
__global__ __launch_bounds__(256) void k_colmax2(const float* __restrict__ pmax,
                                                 int P0, int P1, int P2,
                                                 float* __restrict__ pmax2) {
  __shared__ float sm[2][HID];
  int l = blockIdx.x >> 3, c = blockIdx.x & 7;
  int lo3[3] = {0, P0, P0 + P1};
  int len3[3] = {P0, P1, P2};
  int lo = lo3[l], len = len3[l];
  int f = threadIdx.x & 127, half = threadIdx.x >> 7;
  float mx = -1e30f;
  for (int p = c + 8 * half; p < len; p += 16)
    mx = fmaxf(mx, pmax[(size_t)(lo + p) * HID + f]);
  sm[half][f] = mx;
  __syncthreads();
  if (half == 0) pmax2[(size_t)blockIdx.x * HID + f] = fmaxf(sm[0][f], sm[1][f]);
}

// ---------- final: tiny reduce (24 rows) + MLP head ----------
__global__ __launch_bounds__(1024) void k_final(const float* __restrict__ pmax2,
                        const float* __restrict__ W1, const float* __restrict__ b1,
                        const float* __restrict__ W2, const float* __restrict__ b2,
                        float* __restrict__ out) {
  __shared__ float sxs[3 * HID];
  __shared__ float red[8][HID];
  __shared__ float h1[HID];
  int f = threadIdx.x & 127, ch = threadIdx.x >> 7;
  if (ch < 3) {
    float mx = pmax2[(size_t)(ch * 8) * HID + f];
#pragma unroll
    for (int u = 1; u < 8; ++u) mx = fmaxf(mx, pmax2[(size_t)(ch * 8 + u) * HID + f]);
    sxs[ch * HID + f] = mx;
  }
  __syncthreads();
  float acc = 0.f;
  for (int c = ch * 48; c < (ch + 1) * 48; ++c) acc += sxs[c] * W1[c * HID + f];
  red[ch][f] = acc;
  __syncthreads();
  if (ch == 0) {
    float a = b1[f];
#pragma unroll
    for (int u = 0; u < 8; ++u) a += red[u][f];
    h1[f] = a > 0.f ? a : 0.f;
  }
  __syncthreads();
  if (threadIdx.x < 5) {
    float a = b2[threadIdx.x];
    for (int c = 0; c < HID; ++c) a += h1[c] * W2[c * 5 + threadIdx.x];
    out[threadIdx.x] = a;
  }
}

extern "C" void kernel_launch(void* const* d_in, const int* in_sizes, int n_in,
                              void* d_out, int out_size, void* d_ws, size_t ws_size,
                              hipStream_t stream) {
  const float* x_in   = (const float*)d_in[0];
  const float* pos_in = (const float*)d_in[1];
  const int*   ei     = (const int*)d_in[2];
  const float* Wrel   = (const float*)d_in[3];
  const float* brel   = (const float*)d_in[4];
  const float* Wroot  = (const float*)d_in[5];
  const float* Wprel  = (const float*)d_in[6];
  const float* bprel  = (const float*)d_in[7];
  const float* Wproot = (const float*)d_in[8];
  const float* W1     = (const float*)d_in[9];
  const float* b1     = (const float*)d_in[10];
  const float* W2     = (const float*)d_in[11];
  const float* b2     = (const float*)d_in[12];
  float* out = (float*)d_out;

  const int N0 = in_sizes[0] / HID;   // 20000
  const int P0 = (N0 / 2) / PR, P1 = (N0 / 4) / PR, P2 = (N0 / 8) / PR;  // 500/250/125

  char* w = (char*)d_ws;
  float*    xB     = (float*)w;    w += (size_t)N0 * HID * 4;
  float*    xA     = (float*)w;    w += (size_t)(N0 / 2) * HID * 4;
  float*    score  = (float*)w;    w += (size_t)N0 * 4;
  unsigned* key    = (unsigned*)w; w += (size_t)N0 * 4;
  float*    ubuf   = (float*)w;    w += (size_t)N0 * 4;
  float*    vbuf   = (float*)w;    w += (size_t)N0 * 4;
  int*      srcbuf = (int*)w;      w += (size_t)(N0 / 2) * 8 * 4;
  int*      permb  = (int*)w;      w += (size_t)(N0 / 2) * 4;
  int*      snode  = (int*)w;      w += (size_t)(N0 / 2) * 4;
  float2*   sposA  = (float2*)w;   w += (size_t)(N0 / 2) * 8;
  float2*   sposB  = (float2*)w;   w += (size_t)(N0 / 2) * 8;
  float*    pmax   = (float*)w;    w += (size_t)(P0 + P1 + P2) * HID * 4;
  float*    pmax2  = (float*)w;    w += (size_t)24 * HID * 4;
  // single zeroed region: [ghist 3x4KB][cnt 16 ints][counts 2x16KB][zcur 2x16KB]
  unsigned* ghistB = (unsigned*)w; w += 3 * 1024 * 4;
  int*      cnt    = (int*)w;      w += 16 * 4;          // candCnt[3], selCnt[3]
  int*      countsB= (int*)w;      w += 2 * MAXCELLS * 4;
  int*      zcurB  = (int*)w;      w += 2 * MAXCELLS * 4;
  const size_t ZERO_BYTES = 3 * 1024 * 4 + 16 * 4 + 4 * MAXCELLS * 4;
  unsigned long long* T64 = (unsigned long long*)w; w += 16;
  unsigned* BA     = (unsigned*)w; w += 16;
  unsigned long long* candbuf = (unsigned long long*)w; w += CAND_CAP * 8;
  int*      starts = (int*)w;      w += MAXCELLS * 4;
  (void)ws_size; (void)n_in; (void)out_size;

  hipMemsetAsync(ghistB, 0, ZERO_BYTES, stream);   // one upfront zeroing (captured)

  int n = N0;
  const float* xcur   = x_in;
  const float* poscur = pos_in;
  const int*   srccur = ei;
  int Poff = 0;

  for (int l = 0; l < 3; ++l) {
    const int kk = n / 2;
    int Gg = (int)ceilf(sqrtf((float)kk / 2.5f));
    if (Gg > 64) Gg = 64;
    if (Gg < 1) Gg = 1;
    int cells = Gg * Gg;
    float cw = 100.f / (float)Gg;
    float inv_w = (float)Gg / 100.f;
    int sblocks = (n + 255) / 256;
    unsigned* ghist = ghistB + l * 1024;
    int* counts = countsB + (l < 2 ? l : 0) * MAXCELLS;
    int* zcur   = zcurB + (l < 2 ? l : 0) * MAXCELLS;

    if (l < 2) {
      k_conv_fused<6><<<(n + CRPB - 1) / CRPB, 256, 0, stream>>>(xcur, srccur, n, 1.f / 6.f,
          Wrel + l * HID * HID, Wroot + l * HID * HID, brel + l * HID,
          Wprel + l * HID, Wproot + l * HID, xB, ubuf, vbuf);
      k_score_lite<6><<<sblocks, 256, 0, stream>>>(ubuf, vbuf, srccur, bprel + l,
                                                   n, score, key, ghist);
    } else {
      k_conv_fused<8><<<(n + CRPB - 1) / CRPB, 256, 0, stream>>>(xcur, srccur, n, 1.f / 8.f,
          Wrel + l * HID * HID, Wroot + l * HID * HID, brel + l * HID,
          Wprel + l * HID, Wproot + l * HID, xB, ubuf, vbuf);
      k_score_lite<8><<<sblocks, 256, 0, stream>>>(ubuf, vbuf, srccur, bprel + l,
                                                   n, score, key, ghist);
    }
    k_collect<<<sblocks, 256, 0, stream>>>(key, n, kk, ghist, BA, candbuf, cnt + 2 * l);
    k_refine<<<1, 1024, CAND_CAP * 8, stream>>>(candbuf, cnt + 2 * l, BA, kk, T64);
    k_sel<<<sblocks, 256, 0, stream>>>(key, n, T64, permb, cnt + 2 * l + 1,
                                       poscur, counts, Gg, inv_w, (l < 2) ? 1 : 0);

    float2* sposL = (l == 0) ? sposA : sposB;
    int store = (l < 2) ? 1 : 0;
    const int* poolmap = permb;          // l==2: pool directly from perm
    if (l < 2) {
      k_scatterS<<<(kk + 255) / 256, 256, 0, stream>>>(permb, kk, poscur, Gg, cells, inv_w,
                                                       counts, starts, zcur, sposL, snode);
      poolmap = snode;
    }
    k_pool_pmax<PR><<<kk / PR, 256, 0, stream>>>(xB, score, poolmap, xA, store,
                                                 pmax + (size_t)Poff * HID);
    Poff += kk / PR;
    n = kk;
    if (l == 0) {
      k_knn_wave<6><<<(n + 3) / 4, 256, 0, stream>>>(sposL, starts, counts,
                                                     n, Gg, cw, inv_w, srcbuf);
    } else if (l == 1) {
      k_knn_wave<8><<<(n + 3) / 4, 256, 0, stream>>>(sposL, starts, counts,
                                                     n, Gg, cw, inv_w, srcbuf);
    }
    xcur = xA; poscur = (const float*)sposL; srccur = srcbuf;
  }
  k_colmax2<<<24, 256, 0, stream>>>(pmax, P0, P1, P2, pmax2);
  k_final<<<1, 1024, 0, stream>>>(pmax2, W1, b1, W2, b2, out);
}

// Round 25
// 235.754 us; speedup vs baseline: 1.2604x; 1.2604x over previous
//
#include <hip/hip_runtime.h>
#include <hip/hip_bf16.h>
#include <math.h>

#define HID 128
#define PR 20      // rows per pool block
#define CRPB 32    // conv rows per block
#define CAND_CAP 8192
#define MAXCELLS 4096

__device__ inline int wave_iscan(int v, int lane) {   // inclusive scan within 64-lane wave
#pragma unroll
  for (int off = 1; off < 64; off <<= 1) {
    int o = __shfl_up(v, off, 64);
    if (lane >= off) v += o;
  }
  return v;
}

// ---------- fused mean-gather + GraphConv + score-scalar epilogue (r20/r23 config) ----------
template <int K>
__global__ __launch_bounds__(256) void k_conv_fused(
    const float* __restrict__ x, const int* __restrict__ src, int n, float invk,
    const float* __restrict__ Wrel, const float* __restrict__ Wroot,
    const float* __restrict__ brel,
    const float* __restrict__ wprel, const float* __restrict__ wproot,
    float* __restrict__ out, float* __restrict__ uo, float* __restrict__ vo) {
  __shared__ float4 sagg4[CRPB][HID / 4];
  __shared__ float4 sx4[CRPB][HID / 4];
  __shared__ int ssrc[CRPB * K];
  int t = threadIdx.x;
  int i0 = blockIdx.x * CRPB;
  const int nK = n * K;
  for (int s = t; s < CRPB * K; s += 256) {
    int gi = i0 * K + s;
    int v = (gi < nK) ? src[gi] : 0;
    ssrc[s] = ((unsigned)v < (unsigned)n) ? v : 0;
  }
  __syncthreads();
  {
    int fq = t & 31, h = t >> 5;
    const float4* x4 = (const float4*)x;
    for (int r = h; r < CRPB; r += 8) {
      int row = i0 + r;
      float4 s = make_float4(0.f, 0.f, 0.f, 0.f);
      float4 xv = make_float4(0.f, 0.f, 0.f, 0.f);
      if (row < n) {
#pragma unroll
        for (int j = 0; j < K; ++j) {
          float4 xx = x4[(size_t)ssrc[r * K + j] * 32 + fq];
          s.x += xx.x; s.y += xx.y; s.z += xx.z; s.w += xx.w;
        }
        xv = x4[(size_t)row * 32 + fq];
      }
      s.x *= invk; s.y *= invk; s.z *= invk; s.w *= invk;
      sagg4[r][fq] = s;
      sx4[r][fq] = xv;
    }
  }
  __syncthreads();
  int q = t & 31, rg = t >> 5;
  const float4* Wrel4  = (const float4*)Wrel;
  const float4* Wroot4 = (const float4*)Wroot;
  float4 bq = ((const float4*)brel)[q];
  float4 acc[4];
#pragma unroll
  for (int rr = 0; rr < 4; ++rr) acc[rr] = bq;
  int rbase = rg * 4;
#pragma unroll 2
  for (int cq = 0; cq < HID / 4; ++cq) {
    float4 w1[4], w2[4];
#pragma unroll
    for (int uu = 0; uu < 4; ++uu) {
      w1[uu] = Wrel4[(cq * 4 + uu) * 32 + q];
      w2[uu] = Wroot4[(cq * 4 + uu) * 32 + q];
    }
#pragma unroll
    for (int rr = 0; rr < 4; ++rr) {
      float4 a  = sagg4[rbase + rr][cq];
      float4 xx = sx4[rbase + rr][cq];
      acc[rr].x += a.x*w1[0].x + a.y*w1[1].x + a.z*w1[2].x + a.w*w1[3].x
                 + xx.x*w2[0].x + xx.y*w2[1].x + xx.z*w2[2].x + xx.w*w2[3].x;
      acc[rr].y += a.x*w1[0].y + a.y*w1[1].y + a.z*w1[2].y + a.w*w1[3].y
                 + xx.x*w2[0].y + xx.y*w2[1].y + xx.z*w2[2].y + xx.w*w2[3].y;
      acc[rr].z += a.x*w1[0].z + a.y*w1[1].z + a.z*w1[2].z + a.w*w1[3].z
                 + xx.x*w2[0].z + xx.y*w2[1].z + xx.z*w2[2].z + xx.w*w2[3].z;
      acc[rr].w += a.x*w1[0].w + a.y*w1[1].w + a.z*w1[2].w + a.w*w1[3].w
                 + xx.x*w2[0].w + xx.y*w2[1].w + xx.z*w2[2].w + xx.w*w2[3].w;
    }
  }
  float4 wplq = ((const float4*)wprel)[q];
  float4 wprq = ((const float4*)wproot)[q];
#pragma unroll
  for (int rr = 0; rr < 4; ++rr) {
    int row = i0 + rbase + rr;
    float4 v = acc[rr];
    v.x = v.x > 0.f ? v.x : 0.f;
    v.y = v.y > 0.f ? v.y : 0.f;
    v.z = v.z > 0.f ? v.z : 0.f;
    v.w = v.w > 0.f ? v.w : 0.f;
    float pu = 0.f, pv = 0.f;
    if (row < n) {
      ((float4*)out)[(size_t)row * 32 + q] = v;
      pu = v.x * wplq.x + v.y * wplq.y + v.z * wplq.z + v.w * wplq.w;
      pv = v.x * wprq.x + v.y * wprq.y + v.z * wprq.z + v.w * wprq.w;
    }
#pragma unroll
    for (int o = 16; o; o >>= 1) {
      pu += __shfl_down(pu, o, 32);
      pv += __shfl_down(pv, o, 32);
    }
    if (q == 0 && row < n) { uo[row] = pu; vo[row] = pv; }
  }
}

// ---------- scalar score + fused per-block 1024-bin histogram ----------
template <int K>
__global__ __launch_bounds__(256) void k_score_lite(
    const float* __restrict__ u, const float* __restrict__ v,
    const int* __restrict__ src, const float* __restrict__ bprel,
    int n, float* __restrict__ score, unsigned* __restrict__ key,
    unsigned* __restrict__ ghist) {
  __shared__ unsigned lh[1024];
  int t = threadIdx.x;
#pragma unroll
  for (int uu = 0; uu < 4; ++uu) lh[t + uu * 256] = 0u;
  __syncthreads();
  int i = blockIdx.x * 256 + t;
  if (i < n) {
    float s = v[i] + bprel[0];
#pragma unroll
    for (int j = 0; j < K; ++j) s += u[src[i * K + j]];
    float sc = tanhf(s);
    score[i] = sc;
    unsigned bb = __float_as_uint(sc);
    unsigned k2 = (bb & 0x80000000u) ? ~bb : (bb | 0x80000000u);
    key[i] = k2;
    atomicAdd(&lh[k2 >> 22], 1u);
  }
  __syncthreads();
#pragma unroll
  for (int uu = 0; uu < 4; ++uu) {
    unsigned vv = lh[t + uu * 256];
    if (vv) atomicAdd(&ghist[t + uu * 256], vv);
  }
}

// ---------- collect: inline boundary-bin pick + u64 candidate append ----------
__global__ __launch_bounds__(256) void k_collect(
    const unsigned* __restrict__ key, int n, int kk,
    const unsigned* __restrict__ ghist,
    unsigned* __restrict__ BA, unsigned long long* __restrict__ candbuf,
    int* __restrict__ candCnt) {
  __shared__ int wt[4];
  __shared__ unsigned shB, shAbove;
  int t = threadIdx.x;             // 256
  int lane = t & 63, wid = t >> 6;
  unsigned h[4]; int s = 0;
#pragma unroll
  for (int uu = 0; uu < 4; ++uu) { h[uu] = ghist[t * 4 + uu]; s += (int)h[uu]; }
  int is = wave_iscan(s, lane);
  if (lane == 63) wt[wid] = is;
  __syncthreads();
  int b = 0, tot = 0;
#pragma unroll
  for (int w2 = 0; w2 < 4; ++w2) { int ss = wt[w2]; if (w2 < wid) b += ss; tot += ss; }
  int c = b + is - s;
#pragma unroll
  for (int uu = 0; uu < 4; ++uu) {
    c += (int)h[uu];
    unsigned above_strict = (unsigned)(tot - c);
    unsigned above_incl = above_strict + h[uu];
    if (above_incl >= (unsigned)kk && above_strict < (unsigned)kk) {
      shB = (unsigned)(t * 4 + uu);
      shAbove = above_strict;
    }
  }
  __syncthreads();
  unsigned B = shB;
  if (blockIdx.x == 0 && t == 0) { BA[0] = B; BA[1] = shAbove; }
  int i = blockIdx.x * 256 + t;
  unsigned long long lmask = (1ull << lane) - 1ull;
  unsigned kv = (i < n) ? key[i] : 0u;
  bool m = (i < n) && ((kv >> 22) == B);
  unsigned long long mm = __ballot(m);
  if (mm) {
    int leader = (int)(__ffsll((long long)mm) - 1);
    int base = 0;
    if (lane == leader) base = atomicAdd(candCnt, (int)__popcll(mm));
    base = __shfl(base, leader, 64);
    if (m) {
      int p = base + (int)__popcll(mm & lmask);
      if (p < CAND_CAP) candbuf[p] = ((unsigned long long)kv << 32) | (unsigned)(~i);
    }
  }
}

// ---------- refine 54 remaining bits of unique key64 -> exact T64 ----------
__global__ __launch_bounds__(1024) void k_refine(
    const unsigned long long* __restrict__ candbuf, const int* __restrict__ candCnt,
    const unsigned* __restrict__ BA, int kk, unsigned long long* __restrict__ T64) {
  extern __shared__ unsigned long long cands[];   // CAND_CAP u64 = 64 KB
  __shared__ unsigned hist256[256];
  __shared__ unsigned long long sh_prefix;
  __shared__ unsigned sh_remain;
  __shared__ int wtB[4];
  int t = threadIdx.x;
  int lane = t & 63, wid = t >> 6;
  unsigned B = BA[0], above = BA[1];
  int cnt = *candCnt; if (cnt > CAND_CAP) cnt = CAND_CAP;
  for (int i = t; i < cnt; i += 1024) cands[i] = candbuf[i];
  if (t == 0) {
    sh_prefix = ((unsigned long long)B) << 54;
    sh_remain = (unsigned)(kk - (int)above);
  }
  __syncthreads();
  const int shifts[7] = {46, 38, 30, 22, 14, 6, 0};
  for (int p = 0; p < 7; ++p) {
    int shift = shifts[p];
    int bits = (p == 6) ? 6 : 8;
    unsigned mask = (1u << bits) - 1u;
    unsigned long long himask = (p == 0) ? (~0ull << 54)
                                         : (~0ull << (shifts[p - 1]));
    unsigned long long prefix = sh_prefix;
    unsigned rem = sh_remain;
    if (t < 256) hist256[t] = 0u;
    __syncthreads();
    for (int i = t; i < cnt; i += 1024) {
      unsigned long long cc = cands[i];
      if ((cc & himask) == prefix)
        atomicAdd(&hist256[(unsigned)((cc >> shift) & mask)], 1u);
    }
    __syncthreads();
    int hv = (t < 256) ? (int)hist256[t] : 0;
    int iv = wave_iscan(hv, lane);
    if (t < 256 && lane == 63) wtB[wid] = iv;
    __syncthreads();
    if (t < 256) {
      int b = 0, tot = 0;
#pragma unroll
      for (int w2 = 0; w2 < 4; ++w2) { int s = wtB[w2]; if (w2 < wid) b += s; tot += s; }
      unsigned val = (unsigned)(iv + b);
      unsigned sstrict = (unsigned)tot - val;
      if ((unsigned)t <= mask && sstrict < rem && sstrict + (unsigned)hv >= rem) {
        sh_prefix = prefix | ((unsigned long long)t << shift);
        sh_remain = rem - sstrict;
      }
    }
    __syncthreads();
  }
  if (t == 0) T64[0] = sh_prefix;     // unique k-th largest key64
}

// ---------- compaction: keep key64 >= T64 (exactly kk) + cell counting ----------
__global__ void k_sel(const unsigned* __restrict__ key, int n,
                      const unsigned long long* __restrict__ T64,
                      int* __restrict__ perm, int* __restrict__ cntSel,
                      const float* __restrict__ pos_prev, int* __restrict__ counts,
                      int Gg, float inv_w, int docount) {
  int i = blockIdx.x * blockDim.x + threadIdx.x;
  int lane = threadIdx.x & 63;
  unsigned long long lmask = (1ull << lane) - 1ull;
  unsigned long long T = T64[0];
  bool g = false;
  if (i < n) {
    unsigned long long k64 = ((unsigned long long)key[i] << 32) | (unsigned)(~i);
    g = (k64 >= T);
  }
  unsigned long long mg = __ballot(g);
  if (mg) {
    int leader = (int)(__ffsll((long long)mg) - 1);
    int base = 0;
    if (lane == leader) base = atomicAdd(cntSel, (int)__popcll(mg));
    base = __shfl(base, leader, 64);
    if (g) perm[base + (int)__popcll(mg & lmask)] = i;
  }
  if (g && docount) {
    float px = pos_prev[i * 2], py = pos_prev[i * 2 + 1];
    int cx = min(Gg - 1, max(0, (int)(px * inv_w)));
    int cy = min(Gg - 1, max(0, (int)(py * inv_w)));
    atomicAdd(&counts[cy * Gg + cx], 1);
  }
}

// ---------- spatial scatter: perm -> spatial order map (snode) + spos ----------
__global__ __launch_bounds__(256) void k_scatterS(
    const int* __restrict__ perm, int kk, const float* __restrict__ pos_prev,
    int Gg, int cells, float inv_w,
    const int* __restrict__ counts, int* __restrict__ startsg, int* __restrict__ zcur,
    float2* __restrict__ spos, int* __restrict__ snode) {
  __shared__ int sstarts[MAXCELLS];
  __shared__ int wsum[4];
  int t = threadIdx.x;
  int lane = t & 63, wid = t >> 6;
  int base16 = t * 16;
  int c0[16]; int s = 0;
#pragma unroll
  for (int u = 0; u < 16; ++u) {
    int idx = base16 + u;
    c0[u] = (idx < cells) ? counts[idx] : 0;
    s += c0[u];
  }
  int is = wave_iscan(s, lane);
  if (lane == 63) wsum[wid] = is;
  __syncthreads();
  int b = 0;
#pragma unroll
  for (int w2 = 0; w2 < 4; ++w2) { if (w2 < wid) b += wsum[w2]; }
  int excl = b + is - s;
#pragma unroll
  for (int u = 0; u < 16; ++u) {
    int idx = base16 + u;
    if (idx < cells) { sstarts[idx] = excl; excl += c0[u]; }
  }
  __syncthreads();
  if (blockIdx.x == 0) {
    for (int c = t; c < cells; c += 256) startsg[c] = sstarts[c];
  }
  int j = blockIdx.x * 256 + t;
  if (j < kk) {
    int node = perm[j];
    float px = pos_prev[node * 2], py = pos_prev[node * 2 + 1];
    int cx = min(Gg - 1, max(0, (int)(px * inv_w)));
    int cy = min(Gg - 1, max(0, (int)(py * inv_w)));
    int cell = cy * Gg + cx;
    int pp = sstarts[cell] + atomicAdd(&zcur[cell], 1);
    spos[pp] = make_float2(px, py);
    snode[pp] = node;
  }
}

// ---------- pooled gather in SPATIAL order + per-block column-max ----------
template <int R>
__global__ __launch_bounds__(256) void k_pool_pmax(
    const float* __restrict__ x, const float* __restrict__ score,
    const int* __restrict__ snode,
    float* __restrict__ xout, int store, float* __restrict__ pmax) {
  __shared__ float sm[2][HID];
  int f = threadIdx.x & 127;
  int half = threadIdx.x >> 7;
  int j0 = blockIdx.x * R;
  float mx = -1e30f;
  for (int r = half; r < R; r += 2) {
    int j = j0 + r;
    int node = snode[j];
    float v = score[node];
    float val = x[(size_t)node * HID + f] * v;
    if (store) xout[(size_t)j * HID + f] = val;
    mx = fmaxf(mx, val);
  }
  sm[half][f] = mx;
  __syncthreads();
  if (half == 0) pmax[blockIdx.x * HID + f] = fmaxf(sm[0][f], sm[1][f]);
}

// ---------- exact KNN over spatial array; neighbor index = spatial position ----------
template <int K>
__global__ __launch_bounds__(256) void k_knn_wave(const float2* __restrict__ spos,
                           const int* __restrict__ starts, const int* __restrict__ counts,
                           int m, int G, float w, float inv_w, int* __restrict__ src_out) {
  int lane = threadIdx.x & 63;
  int j = blockIdx.x * (blockDim.x >> 6) + (threadIdx.x >> 6);
  if (j >= m) return;
  float2 qp = spos[j];
  int cx = min(G - 1, max(0, (int)(qp.x * inv_w)));
  int cy = min(G - 1, max(0, (int)(qp.y * inv_w)));

  float bd[K]; int bi[K];
#pragma unroll
  for (int t = 0; t < K; ++t) { bd[t] = 1e30f; bi[t] = 0; }

  auto scan_span = [&](int s, int e) {
    for (int p = s + lane; p < e; p += 64) {
      if (p == j) continue;
      float2 pp = spos[p];
      float dx = qp.x - pp.x, dy = qp.y - pp.y;
      float d = dx * dx + dy * dy;
      if (d < bd[K - 1]) {
        float dd = d; int ii = p;
#pragma unroll
        for (int t = 0; t < K; ++t) {
          bool sw = dd < bd[t];
          float od = bd[t]; int oi = bi[t];
          if (sw) { bd[t] = dd; bi[t] = ii; dd = od; ii = oi; }
        }
      }
    }
  };

  {
    int xl = max(0, cx - 1), xh = min(G - 1, cx + 1);
    int y0 = max(0, cy - 1), y1 = min(G - 1, cy + 1);
    int ss[3], ee[3]; int nr = 0;
    for (int y = y0; y <= y1; ++y) {
      int b = y * G;
      ss[nr] = starts[b + xl];
      ee[nr] = starts[b + xh] + counts[b + xh];
      ++nr;
    }
    for (int t = 0; t < nr; ++t) scan_span(ss[t], ee[t]);
  }

  int r = 1;
  unsigned long long mg[K];
  while (true) {
    unsigned long long tmp[K];
#pragma unroll
    for (int t = 0; t < K; ++t)
      tmp[t] = ((unsigned long long)__float_as_uint(bd[t]) << 32) | (unsigned)bi[t];
#pragma unroll
    for (int t = 0; t < K; ++t) {
      unsigned long long mn = tmp[0];
#pragma unroll
      for (int o = 1; o < 64; o <<= 1) {
        unsigned long long ot = __shfl_xor(mn, o, 64);
        if (ot < mn) mn = ot;
      }
      mg[t] = mn;
      if (tmp[0] == mn) {
#pragma unroll
        for (int s2 = 0; s2 < K - 1; ++s2) tmp[s2] = tmp[s2 + 1];
        tmp[K - 1] = ~0ull;
      }
    }
    float kth = __uint_as_float((unsigned)(mg[K - 1] >> 32));
    float bnd = 1e30f;
    if (cx - r > 0)     bnd = fminf(bnd, qp.x - (float)(cx - r) * w);
    if (cx + r < G - 1) bnd = fminf(bnd, (float)(cx + r + 1) * w - qp.x);
    if (cy - r > 0)     bnd = fminf(bnd, qp.y - (float)(cy - r) * w);
    if (cy + r < G - 1) bnd = fminf(bnd, (float)(cy + r + 1) * w - qp.y);
    if (bnd > 1e29f) break;
    float bb = fmaxf(bnd, 0.f) * 0.999f;
    if (kth < bb * bb) break;
    ++r;
    int xl = max(0, cx - r), xh = min(G - 1, cx + r);
    int yt = cy - r, yb = cy + r;
    if (yt >= 0)     { int b = yt * G; scan_span(starts[b + xl], starts[b + xh] + counts[b + xh]); }
    if (yb <= G - 1) { int b = yb * G; scan_span(starts[b + xl], starts[b + xh] + counts[b + xh]); }
    int ylo = max(0, cy - r + 1), yhi = min(G - 1, cy + r - 1);
    for (int y = ylo; y <= yhi; ++y) {
      int b = y * G;
      if (cx - r >= 0)     { int c = b + cx - r; scan_span(starts[c], starts[c] + counts[c]); }
      if (cx + r <= G - 1) { int c = b + cx + r; scan_span(starts[c], starts[c] + counts[c]); }
    }
  }
  if (lane == 0) {
#pragma unroll
    for (int t = 0; t < K; ++t) src_out[j * K + t] = (int)(unsigned)(mg[t] & 0xffffffffu);
  }
}

// ---------- grid-parallel pmax reduction: 24 blocks -> pmax2[3][8][HID] ----------
__global__ __launch_bounds__(256) void k_colmax2(const float* __restrict__ pmax,
                                                 int P0, int P1, int P2,
                                                 float* __restrict__ pmax2) {
  __shared__ float sm[2][HID];
  int l = blockIdx.x >> 3, c = blockIdx.x & 7;
  int lo3[3] = {0, P0, P0 + P1};
  int len3[3] = {P0, P1, P2};
  int lo = lo3[l], len = len3[l];
  int f = threadIdx.x & 127, half = threadIdx.x >> 7;
  float mx = -1e30f;
  for (int p = c + 8 * half; p < len; p += 16)
    mx = fmaxf(mx, pmax[(size_t)(lo + p) * HID + f]);
  sm[half][f] = mx;
  __syncthreads();
  if (half == 0) pmax2[(size_t)blockIdx.x * HID + f] = fmaxf(sm[0][f], sm[1][f]);
}

// ---------- final: tiny reduce (24 rows) + MLP head ----------
__global__ __launch_bounds__(1024) void k_final(const float* __restrict__ pmax2,
                        const float* __restrict__ W1, const float* __restrict__ b1,
                        const float* __restrict__ W2, const float* __restrict__ b2,
                        float* __restrict__ out) {
  __shared__ float sxs[3 * HID];
  __shared__ float red[8][HID];
  __shared__ float h1[HID];
  int f = threadIdx.x & 127, ch = threadIdx.x >> 7;
  if (ch < 3) {
    float mx = pmax2[(size_t)(ch * 8) * HID + f];
#pragma unroll
    for (int u = 1; u < 8; ++u) mx = fmaxf(mx, pmax2[(size_t)(ch * 8 + u) * HID + f]);
    sxs[ch * HID + f] = mx;
  }
  __syncthreads();
  float acc = 0.f;
  for (int c = ch * 48; c < (ch + 1) * 48; ++c) acc += sxs[c] * W1[c * HID + f];
  red[ch][f] = acc;
  __syncthreads();
  if (ch == 0) {
    float a = b1[f];
#pragma unroll
    for (int u = 0; u < 8; ++u) a += red[u][f];
    h1[f] = a > 0.f ? a : 0.f;
  }
  __syncthreads();
  if (threadIdx.x < 5) {
    float a = b2[threadIdx.x];
    for (int c = 0; c < HID; ++c) a += h1[c] * W2[c * 5 + threadIdx.x];
    out[threadIdx.x] = a;
  }
}

extern "C" void kernel_launch(void* const* d_in, const int* in_sizes, int n_in,
                              void* d_out, int out_size, void* d_ws, size_t ws_size,
                              hipStream_t stream) {
  const float* x_in   = (const float*)d_in[0];
  const float* pos_in = (const float*)d_in[1];
  const int*   ei     = (const int*)d_in[2];
  const float* Wrel   = (const float*)d_in[3];
  const float* brel   = (const float*)d_in[4];
  const float* Wroot  = (const float*)d_in[5];
  const float* Wprel  = (const float*)d_in[6];
  const float* bprel  = (const float*)d_in[7];
  const float* Wproot = (const float*)d_in[8];
  const float* W1     = (const float*)d_in[9];
  const float* b1     = (const float*)d_in[10];
  const float* W2     = (const float*)d_in[11];
  const float* b2     = (const float*)d_in[12];
  float* out = (float*)d_out;

  const int N0 = in_sizes[0] / HID;   // 20000
  const int P0 = (N0 / 2) / PR, P1 = (N0 / 4) / PR, P2 = (N0 / 8) / PR;  // 500/250/125

  char* w = (char*)d_ws;
  float*    xB     = (float*)w;    w += (size_t)N0 * HID * 4;
  float*    xA     = (float*)w;    w += (size_t)(N0 / 2) * HID * 4;
  float*    score  = (float*)w;    w += (size_t)N0 * 4;
  unsigned* key    = (unsigned*)w; w += (size_t)N0 * 4;
  float*    ubuf   = (float*)w;    w += (size_t)N0 * 4;
  float*    vbuf   = (float*)w;    w += (size_t)N0 * 4;
  int*      srcbuf = (int*)w;      w += (size_t)(N0 / 2) * 8 * 4;
  int*      permb  = (int*)w;      w += (size_t)(N0 / 2) * 4;
  int*      snode  = (int*)w;      w += (size_t)(N0 / 2) * 4;
  float2*   sposA  = (float2*)w;   w += (size_t)(N0 / 2) * 8;
  float2*   sposB  = (float2*)w;   w += (size_t)(N0 / 2) * 8;
  float*    pmax   = (float*)w;    w += (size_t)(P0 + P1 + P2) * HID * 4;
  float*    pmax2  = (float*)w;    w += (size_t)24 * HID * 4;
  // single zeroed region: [ghist 3x4KB][cnt 16 ints][counts 2x16KB][zcur 2x16KB]
  unsigned* ghistB = (unsigned*)w; w += 3 * 1024 * 4;
  int*      cnt    = (int*)w;      w += 16 * 4;          // candCnt[3], selCnt[3]
  int*      countsB= (int*)w;      w += 2 * MAXCELLS * 4;
  int*      zcurB  = (int*)w;      w += 2 * MAXCELLS * 4;
  const size_t ZERO_BYTES = 3 * 1024 * 4 + 16 * 4 + 4 * MAXCELLS * 4;
  unsigned long long* T64 = (unsigned long long*)w; w += 16;
  unsigned* BA     = (unsigned*)w; w += 16;
  unsigned long long* candbuf = (unsigned long long*)w; w += CAND_CAP * 8;
  int*      starts = (int*)w;      w += MAXCELLS * 4;
  (void)ws_size; (void)n_in; (void)out_size;

  hipMemsetAsync(ghistB, 0, ZERO_BYTES, stream);   // one upfront zeroing (captured)

  int n = N0;
  const float* xcur   = x_in;
  const float* poscur = pos_in;
  const int*   srccur = ei;
  int Poff = 0;

  for (int l = 0; l < 3; ++l) {
    const int kk = n / 2;
    int Gg = (int)ceilf(sqrtf((float)kk / 2.5f));
    if (Gg > 64) Gg = 64;
    if (Gg < 1) Gg = 1;
    int cells = Gg * Gg;
    float cw = 100.f / (float)Gg;
    float inv_w = (float)Gg / 100.f;
    int sblocks = (n + 255) / 256;
    unsigned* ghist = ghistB + l * 1024;
    int* counts = countsB + (l < 2 ? l : 0) * MAXCELLS;
    int* zcur   = zcurB + (l < 2 ? l : 0) * MAXCELLS;

    if (l < 2) {
      k_conv_fused<6><<<(n + CRPB - 1) / CRPB, 256, 0, stream>>>(xcur, srccur, n, 1.f / 6.f,
          Wrel + l * HID * HID, Wroot + l * HID * HID, brel + l * HID,
          Wprel + l * HID, Wproot + l * HID, xB, ubuf, vbuf);
      k_score_lite<6><<<sblocks, 256, 0, stream>>>(ubuf, vbuf, srccur, bprel + l,
                                                   n, score, key, ghist);
    } else {
      k_conv_fused<8><<<(n + CRPB - 1) / CRPB, 256, 0, stream>>>(xcur, srccur, n, 1.f / 8.f,
          Wrel + l * HID * HID, Wroot + l * HID * HID, brel + l * HID,
          Wprel + l * HID, Wproot + l * HID, xB, ubuf, vbuf);
      k_score_lite<8><<<sblocks, 256, 0, stream>>>(ubuf, vbuf, srccur, bprel + l,
                                                   n, score, key, ghist);
    }
    k_collect<<<sblocks, 256, 0, stream>>>(key, n, kk, ghist, BA, candbuf, cnt + 2 * l);
    k_refine<<<1, 1024, CAND_CAP * 8, stream>>>(candbuf, cnt + 2 * l, BA, kk, T64);
    k_sel<<<sblocks, 256, 0, stream>>>(key, n, T64, permb, cnt + 2 * l + 1,
                                       poscur, counts, Gg, inv_w, (l < 2) ? 1 : 0);

    float2* sposL = (l == 0) ? sposA : sposB;
    int store = (l < 2) ? 1 : 0;
    const int* poolmap = permb;          // l==2: pool directly from perm
    if (l < 2) {
      k_scatterS<<<(kk + 255) / 256, 256, 0, stream>>>(permb, kk, poscur, Gg, cells, inv_w,
                                                       counts, starts, zcur, sposL, snode);
      poolmap = snode;
    }
    k_pool_pmax<PR><<<kk / PR, 256, 0, stream>>>(xB, score, poolmap, xA, store,
                                                 pmax + (size_t)Poff * HID);
    Poff += kk / PR;
    n = kk;
    if (l == 0) {
      k_knn_wave<6><<<(n + 3) / 4, 256, 0, stream>>>(sposL, starts, counts,
                                                     n, Gg, cw, inv_w, srcbuf);
    } else if (l == 1) {
      k_knn_wave<8><<<(n + 3) / 4, 256, 0, stream>>>(sposL, starts, counts,
                                                     n, Gg, cw, inv_w, srcbuf);
    }
    xcur = xA; poscur = (const float*)sposL; srccur = srcbuf;
  }
  k_colmax2<<<24, 256, 0, stream>>>(pmax, P0, P1, P2, pmax2);
  k_final<<<1, 1024, 0, stream>>>(pmax2, W1, b1, W2, b2, out);
}